// Round 11
// baseline (215.833 us; speedup 1.0000x reference)
//
#include <hip/hip_runtime.h>
#include <hip/hip_bf16.h>

#define HID 16
#define CLS 40
#define FIN 512
#define TILE 3200     // edges per bucketize block (38KB LDS -> 4 blocks/CU)
#define NBP 512       // padded bucket count (256-node buckets; n <= 131072)
#define CAP 8704      // LDS edge cache per bucket (mean 8192, +5.7 sigma)

typedef unsigned int uint;
typedef unsigned short ushort;

__device__ __forceinline__ ushort f2bf(float f) {
    uint u = __float_as_uint(f);
    u += 0x7FFF + ((u >> 16) & 1);   // round-to-nearest-even
    return (ushort)(u >> 16);
}
__device__ __forceinline__ float bflo(uint u) { return __uint_as_float(u << 16); }
__device__ __forceinline__ float bfhi(uint u) { return __uint_as_float(u & 0xFFFF0000u); }
// decode bf15 weight packed in bits [31:17] (weights are >= 0)
__device__ __forceinline__ float wdec(uint a) {
    return __uint_as_float((a >> 17) << 16);
}

// ================= scan stage 1: per-1024-chunk sums =================
__global__ __launch_bounds__(256) void scan1_k(const int* __restrict__ cnt,
                                               int* __restrict__ bsum, int M) {
    __shared__ int ws[4];
    int b = blockIdx.x, t = threadIdx.x;
    int i0 = b * 1024 + t * 4;
    int s = 0;
#pragma unroll
    for (int q = 0; q < 4; ++q) if (i0 + q < M) s += cnt[i0 + q];
    for (int d = 32; d > 0; d >>= 1) s += __shfl_xor(s, d);
    int lane = t & 63, wid = t >> 6;
    if (lane == 0) ws[wid] = s;
    __syncthreads();
    if (t == 0) bsum[b] = ws[0] + ws[1] + ws[2] + ws[3];
}

// ============ scan stage 2 (fused): block-sum scan + element scan ===========
__global__ __launch_bounds__(256) void scan3_k(const int* __restrict__ cnt,
                                               const int* __restrict__ bsumRaw,
                                               int* __restrict__ sout, int M, int G) {
    __shared__ int sb[1024];
    __shared__ int wsumA[4], wbaseA[4];
    __shared__ int wsumB[4], wbaseB[4];
    int t = threadIdx.x;
    int lane = t & 63, wid = t >> 6;
    {   // exclusive scan of bsumRaw[0..G) into sb (every block redundantly)
        int i0 = t * 4;
        int c[4];
#pragma unroll
        for (int q = 0; q < 4; ++q) c[q] = (i0 + q < G) ? bsumRaw[i0 + q] : 0;
        int s = c[0] + c[1] + c[2] + c[3];
        int v = s;
        for (int d = 1; d < 64; d <<= 1) { int u = __shfl_up(v, d); if (lane >= d) v += u; }
        if (lane == 63) wsumA[wid] = v;
        __syncthreads();
        if (t == 0) { int r = 0; for (int q = 0; q < 4; ++q) { wbaseA[q] = r; r += wsumA[q]; } }
        __syncthreads();
        int o = v - s + wbaseA[wid];
#pragma unroll
        for (int q = 0; q < 4; ++q) { sb[i0 + q] = o; o += c[q]; }
    }
    __syncthreads();
    {   // element scan of this block's 1024 chunk
        int b = blockIdx.x;
        int i0 = b * 1024 + t * 4;
        int c[4];
#pragma unroll
        for (int q = 0; q < 4; ++q) c[q] = (i0 + q < M) ? cnt[i0 + q] : 0;
        int s = c[0] + c[1] + c[2] + c[3];
        int v = s;
        for (int d = 1; d < 64; d <<= 1) { int u = __shfl_up(v, d); if (lane >= d) v += u; }
        if (lane == 63) wsumB[wid] = v;
        __syncthreads();
        if (t == 0) { int r = 0; for (int q = 0; q < 4; ++q) { wbaseB[q] = r; r += wsumB[q]; } }
        __syncthreads();
        int o = v - s + wbaseB[wid] + sb[b];
#pragma unroll
        for (int q = 0; q < 4; ++q) {
            if (i0 + q < M) { sout[i0 + q] = o; o += c[q]; }
        }
    }
}

// ================= pass A: bucketize by col>>8 (LDS atomics only) ===========
__global__ __launch_bounds__(256) void bk_count_k(const int* __restrict__ col,
                                                  int* __restrict__ bcnt,
                                                  int E, int NB, int ABLK) {
    __shared__ int hist[NBP];
    int t = threadIdx.x, blk = blockIdx.x;
    for (int i = t; i < NBP; i += 256) hist[i] = 0;
    __syncthreads();
    int e0 = blk * TILE, e1 = min(E, e0 + TILE);
    for (int e = e0 + t; e < e1; e += 256) atomicAdd(&hist[col[e] >> 8], 1);
    __syncthreads();
    for (int b = t; b < NB; b += 256) bcnt[b * ABLK + blk] = hist[b];
}

__global__ __launch_bounds__(256) void bk_scatter_k(const int* __restrict__ row,
                                                    const int* __restrict__ col,
                                                    const float* __restrict__ w,
                                                    const int* __restrict__ sbcnt,
                                                    int2* __restrict__ bpack,
                                                    int E, int NB, int ABLK) {
    __shared__ int2 stage[TILE];
    __shared__ ushort stageB[TILE];
    __shared__ int hist[NBP], cur[NBP], gbase[NBP];
    __shared__ int wsum[4], wbase[4];
    int t = threadIdx.x, blk = blockIdx.x;
    for (int i = t; i < NBP; i += 256) hist[i] = 0;
    __syncthreads();
    int e0 = blk * TILE, e1 = min(E, e0 + TILE);
    for (int e = e0 + t; e < e1; e += 256) atomicAdd(&hist[col[e] >> 8], 1);
    __syncthreads();
    {
        int c0 = hist[2 * t], c1 = hist[2 * t + 1];
        int s = c0 + c1;
        int lane = t & 63, wid = t >> 6;
        int v = s;
        for (int d = 1; d < 64; d <<= 1) { int u = __shfl_up(v, d); if (lane >= d) v += u; }
        if (lane == 63) wsum[wid] = v;
        __syncthreads();
        if (t == 0) { int r = 0; for (int q = 0; q < 4; ++q) { wbase[q] = r; r += wsum[q]; } }
        __syncthreads();
        int excl = v - s + wbase[wid];
        int s0 = 2 * t, s1 = 2 * t + 1;
        cur[s0] = excl;
        gbase[s0] = ((s0 < NB) ? sbcnt[s0 * ABLK + blk] : 0) - excl;
        cur[s1] = excl + c0;
        gbase[s1] = ((s1 < NB) ? sbcnt[s1 * ABLK + blk] : 0) - (excl + c0);
    }
    __syncthreads();
    for (int e = e0 + t; e < e1; e += 256) {
        int c = col[e];
        int bkt = c >> 8, cl = c & 255;
        int lr = atomicAdd(&cur[bkt], 1);
        stage[lr] = make_int2(row[e] | (cl << 17), __float_as_int(w[e]));
        stageB[lr] = (ushort)bkt;
    }
    __syncthreads();
    int cntE = e1 - e0;
    for (int s = t; s < cntE; s += 256) {
        int bkt = stageB[s];
        bpack[gbase[bkt] + s] = stage[s];
    }
}

// ====== pass B (fused, 512 thr): LDS edge cache + count + scan + dinv + place
__global__ __launch_bounds__(512) void seg_build_k(const int2* __restrict__ bpack,
                                                   const int* __restrict__ sbcnt,
                                                   int* __restrict__ off,
                                                   float* __restrict__ dinv,
                                                   uint* __restrict__ fin,
                                                   int E, int NB, int ABLK, int NN) {
    __shared__ int2 ldsE[CAP];
    __shared__ int cntL[256];
    __shared__ float degL[256];
    __shared__ int curL[256];
    __shared__ int wtot[8];
    int t = threadIdx.x, b = blockIdx.x;
    if (t < 256) { cntL[t] = 0; degL[t] = 0.f; }
    __syncthreads();
    int p0 = sbcnt[b * ABLK];
    int p1 = (b + 1 < NB) ? sbcnt[(b + 1) * ABLK] : E;
    int m = p1 - p0;
    for (int j = t; j < m; j += 512) {
        int2 pk = bpack[p0 + j];
        if (j < CAP) ldsE[j] = pk;
        int cl = (pk.x >> 17) & 255;
        atomicAdd(&cntL[cl], 1);
        atomicAdd(&degL[cl], __int_as_float(pk.y));
    }
    __syncthreads();
    // exclusive scan of cntL[0..255] (threads 256..511 carry zeros)
    int c = (t < 256) ? cntL[t] : 0;
    int lane = t & 63, wid = t >> 6;
    int v = c;
    for (int d = 1; d < 64; d <<= 1) { int u = __shfl_up(v, d); if (lane >= d) v += u; }
    if (lane == 63) wtot[wid] = v;
    __syncthreads();
    if (t < 256) {
        int base = p0;
        for (int q = 0; q < wid; ++q) base += wtot[q];   // wid 0..3
        int excl = base + v - c;
        int node = b * 256 + t;
        off[node] = excl;
        curL[t] = excl;
        dinv[node] = rsqrtf(1.0f + degL[t]);   // +1 = self-loop weight
    }
    if (b == NB - 1 && t == 0) off[NN] = E;
    __syncthreads();
    for (int j = t; j < m; j += 512) {
        int2 pk = (j < CAP) ? ldsE[j] : bpack[p0 + j];   // overflow tail: re-read
        uint src = (uint)pk.x & 0x1FFFFu;
        int cl = (pk.x >> 17) & 255;
        uint u = (uint)pk.y + 0x8000u;          // raw w >= 0, bf15 round
        int pos = atomicAdd(&curL[cl], 1);
        fin[pos] = src | ((u >> 16) << 17);
    }
}

// ====== g = dinv .* (x @ W1), bf16x2-packed; 4 lanes/row, coalesced x =======
// LDS W1 layout padded: float4 index = k*4 + j + (k>>2)  (one pad f4 per 4 rows)
// -> per-instruction sub-lane stride = 17 f4 = 272 B: conflict-free (R8-verified)
__global__ __launch_bounds__(256) void gemm1_k(const float* __restrict__ x,
                                               const float* __restrict__ W1,
                                               const float* __restrict__ dinv,
                                               uint* __restrict__ g, int n) {
    __shared__ float4 w1s[FIN * HID / 4 + FIN / 4];   // 2176 f4 = 34816 B
    {
        const float4* s4 = (const float4*)W1;
        for (int i = threadIdx.x; i < FIN * HID / 4; i += 256)
            w1s[i + (i >> 4)] = s4[i];
    }
    __syncthreads();
    int r = blockIdx.x * 64 + (threadIdx.x >> 2);
    if (r >= n) return;
    int sub = threadIdx.x & 3;
    const float4* xr = (const float4*)(x + (size_t)r * FIN);
    float acc[HID];
#pragma unroll
    for (int c = 0; c < HID; ++c) acc[c] = 0.f;
    for (int q = 0; q < FIN / 16; ++q) {
        float4 xv = xr[q * 4 + sub];
        int kbase = q * 16 + sub * 4;                       // this lane's 4 rows
        const float4* w4 = &w1s[kbase * 4 + (kbase >> 2)];  // padded base
#pragma unroll
        for (int e = 0; e < 4; ++e) {
            float xe = (e == 0) ? xv.x : (e == 1) ? xv.y : (e == 2) ? xv.z : xv.w;
#pragma unroll
            for (int j = 0; j < 4; ++j) {
                float4 wv = w4[e * 4 + j];
                acc[4 * j + 0] += xe * wv.x;
                acc[4 * j + 1] += xe * wv.y;
                acc[4 * j + 2] += xe * wv.z;
                acc[4 * j + 3] += xe * wv.w;
            }
        }
    }
    // butterfly: all 4 lanes get full sums
#pragma unroll
    for (int c = 0; c < HID; ++c) {
        acc[c] += __shfl_xor(acc[c], 1, 4);
        acc[c] += __shfl_xor(acc[c], 2, 4);
    }
    // lane sub owns features 4*sub .. 4*sub+3 (constant-index selects)
    float f0, f1, f2, f3;
    {
        float t0 = (sub & 2) ? acc[8] : acc[0], t4 = (sub & 2) ? acc[12] : acc[4];
        f0 = (sub & 1) ? t4 : t0;
        float u0 = (sub & 2) ? acc[9] : acc[1], u4 = (sub & 2) ? acc[13] : acc[5];
        f1 = (sub & 1) ? u4 : u0;
        float v0 = (sub & 2) ? acc[10] : acc[2], v4 = (sub & 2) ? acc[14] : acc[6];
        f2 = (sub & 1) ? v4 : v0;
        float w0 = (sub & 2) ? acc[11] : acc[3], w4v = (sub & 2) ? acc[15] : acc[7];
        f3 = (sub & 1) ? w4v : w0;
    }
    float di = dinv[r];
    uint lo = (uint)f2bf(di * f0) | ((uint)f2bf(di * f1) << 16);
    uint hi = (uint)f2bf(di * f2) | ((uint)f2bf(di * f3) << 16);
    ((uint2*)(g + (size_t)r * 8))[sub] = make_uint2(lo, hi);
}

// ===== layer-1 gather (4 lanes/node, bf16x4 per lane via uint2):
//   g1 = dinv .* relu(dinv .* (Σ w g_src + g_i) + b1)
__global__ __launch_bounds__(256) void agg1_k(const uint2* __restrict__ g2,
                                              const float* __restrict__ dinv,
                                              const int* __restrict__ off,
                                              const uint* __restrict__ fin,
                                              const float* __restrict__ bb,
                                              uint2* __restrict__ g12, int n) {
    int tid = blockIdx.x * 256 + threadIdx.x;
    int i = tid >> 2;
    if (i >= n) return;
    int lane = tid & 3;
    uint2 sv = g2[(size_t)i * 4 + lane];
    float a0 = bflo(sv.x), a1 = bfhi(sv.x), a2 = bflo(sv.y), a3 = bfhi(sv.y);
    float b0 = 0.f, b1v = 0.f, b2v = 0.f, b3 = 0.f;
    float c0 = 0.f, c1 = 0.f, c2 = 0.f, c3 = 0.f;
    float d0 = 0.f, d1 = 0.f, d2 = 0.f, d3 = 0.f;
    int p = off[i], e = off[i + 1];
    for (; p + 3 < e; p += 4) {
        uint fa = fin[p], fb = fin[p + 1], fc = fin[p + 2], fd = fin[p + 3];
        uint2 ga = g2[(size_t)(fa & 0x1FFFFu) * 4 + lane];
        uint2 gb = g2[(size_t)(fb & 0x1FFFFu) * 4 + lane];
        uint2 gc = g2[(size_t)(fc & 0x1FFFFu) * 4 + lane];
        uint2 gd = g2[(size_t)(fd & 0x1FFFFu) * 4 + lane];
        float wa = wdec(fa), wb = wdec(fb), wc = wdec(fc), wd = wdec(fd);
        a0 += wa * bflo(ga.x); a1 += wa * bfhi(ga.x); a2 += wa * bflo(ga.y); a3 += wa * bfhi(ga.y);
        b0 += wb * bflo(gb.x); b1v += wb * bfhi(gb.x); b2v += wb * bflo(gb.y); b3 += wb * bfhi(gb.y);
        c0 += wc * bflo(gc.x); c1 += wc * bfhi(gc.x); c2 += wc * bflo(gc.y); c3 += wc * bfhi(gc.y);
        d0 += wd * bflo(gd.x); d1 += wd * bfhi(gd.x); d2 += wd * bflo(gd.y); d3 += wd * bfhi(gd.y);
    }
    for (; p < e; ++p) {
        uint fa = fin[p];
        uint2 ga = g2[(size_t)(fa & 0x1FFFFu) * 4 + lane];
        float wa = wdec(fa);
        a0 += wa * bflo(ga.x); a1 += wa * bfhi(ga.x); a2 += wa * bflo(ga.y); a3 += wa * bfhi(ga.y);
    }
    float di = dinv[i];
    const float4 bv = *(const float4*)(bb + 4 * lane);
    float v0 = fmaxf(di * ((a0 + b0) + (c0 + d0)) + bv.x, 0.f);
    float v1 = fmaxf(di * ((a1 + b1v) + (c1 + d1)) + bv.y, 0.f);
    float v2 = fmaxf(di * ((a2 + b2v) + (c2 + d2)) + bv.z, 0.f);
    float v3 = fmaxf(di * ((a3 + b3) + (c3 + d3)) + bv.w, 0.f);
    g12[(size_t)i * 4 + lane] =
        make_uint2((uint)f2bf(di * v0) | ((uint)f2bf(di * v1) << 16),
                   (uint)f2bf(di * v2) | ((uint)f2bf(di * v3) << 16));
}

// ===== layer-2 gather + W2 matvec + log_softmax (4 lanes/node) ==============
__global__ __launch_bounds__(256) void agg2out_k(const uint2* __restrict__ g2,
                                                 const float* __restrict__ dinv,
                                                 const int* __restrict__ off,
                                                 const uint* __restrict__ fin,
                                                 const float* __restrict__ W2,
                                                 const float* __restrict__ b2,
                                                 float* __restrict__ out, int n) {
    __shared__ float w2s[HID * CLS];
    __shared__ float b2s[CLS];
    for (int q = threadIdx.x; q < HID * CLS; q += 256) w2s[q] = W2[q];
    if (threadIdx.x < CLS) b2s[threadIdx.x] = b2[threadIdx.x];
    __syncthreads();
    int tid = blockIdx.x * 256 + threadIdx.x;
    int i = tid >> 2;
    if (i >= n) return;    // 4-lane group exits together
    int lane = tid & 3;
    uint2 sv = g2[(size_t)i * 4 + lane];
    float a0 = bflo(sv.x), a1 = bfhi(sv.x), a2 = bflo(sv.y), a3 = bfhi(sv.y);
    float b0 = 0.f, b1v = 0.f, b2v = 0.f, b3 = 0.f;
    float c0 = 0.f, c1 = 0.f, c2 = 0.f, c3 = 0.f;
    float d0 = 0.f, d1 = 0.f, d2 = 0.f, d3 = 0.f;
    int p = off[i], e = off[i + 1];
    for (; p + 3 < e; p += 4) {
        uint fa = fin[p], fb = fin[p + 1], fc = fin[p + 2], fd = fin[p + 3];
        uint2 ga = g2[(size_t)(fa & 0x1FFFFu) * 4 + lane];
        uint2 gb = g2[(size_t)(fb & 0x1FFFFu) * 4 + lane];
        uint2 gc = g2[(size_t)(fc & 0x1FFFFu) * 4 + lane];
        uint2 gd = g2[(size_t)(fd & 0x1FFFFu) * 4 + lane];
        float wa = wdec(fa), wb = wdec(fb), wc = wdec(fc), wd = wdec(fd);
        a0 += wa * bflo(ga.x); a1 += wa * bfhi(ga.x); a2 += wa * bflo(ga.y); a3 += wa * bfhi(ga.y);
        b0 += wb * bflo(gb.x); b1v += wb * bfhi(gb.x); b2v += wb * bflo(gb.y); b3 += wb * bfhi(gb.y);
        c0 += wc * bflo(gc.x); c1 += wc * bfhi(gc.x); c2 += wc * bflo(gc.y); c3 += wc * bfhi(gc.y);
        d0 += wd * bflo(gd.x); d1 += wd * bfhi(gd.x); d2 += wd * bflo(gd.y); d3 += wd * bfhi(gd.y);
    }
    for (; p < e; ++p) {
        uint fa = fin[p];
        uint2 ga = g2[(size_t)(fa & 0x1FFFFu) * 4 + lane];
        float wa = wdec(fa);
        a0 += wa * bflo(ga.x); a1 += wa * bfhi(ga.x); a2 += wa * bflo(ga.y); a3 += wa * bfhi(ga.y);
    }
    float di = dinv[i];
    float v0 = di * ((a0 + b0) + (c0 + d0));   // agg2[i][4*lane+0]
    float v1 = di * ((a1 + b1v) + (c1 + d1));
    float v2 = di * ((a2 + b2v) + (c2 + d2));
    float v3 = di * ((a3 + b3) + (c3 + d3));
    // transpose within 4-lane group: a[k] = agg2[i][k]
    float a[HID];
#pragma unroll
    for (int k = 0; k < 4; ++k) {
        a[4 * k + 0] = __shfl(v0, k, 4);
        a[4 * k + 1] = __shfl(v1, k, 4);
        a[4 * k + 2] = __shfl(v2, k, 4);
        a[4 * k + 3] = __shfl(v3, k, 4);
    }
    // each lane computes classes lane + 4*j, j = 0..9
    float z[10];
#pragma unroll
    for (int j = 0; j < 10; ++j) z[j] = b2s[lane + 4 * j];
#pragma unroll
    for (int k = 0; k < HID; ++k) {
        float ak = a[k];
#pragma unroll
        for (int j = 0; j < 10; ++j) z[j] += ak * w2s[k * CLS + lane + 4 * j];
    }
    float m = z[0];
#pragma unroll
    for (int j = 1; j < 10; ++j) m = fmaxf(m, z[j]);
    m = fmaxf(m, __shfl_xor(m, 1, 4));
    m = fmaxf(m, __shfl_xor(m, 2, 4));
    float s = 0.f;
#pragma unroll
    for (int j = 0; j < 10; ++j) s += __expf(z[j] - m);
    s += __shfl_xor(s, 1, 4);
    s += __shfl_xor(s, 2, 4);
    float l = __logf(s) + m;
    float* o = out + (size_t)i * CLS;
#pragma unroll
    for (int j = 0; j < 10; ++j) o[lane + 4 * j] = z[j] - l;
}

extern "C" void kernel_launch(void* const* d_in, const int* in_sizes, int n_in,
                              void* d_out, int out_size, void* d_ws, size_t ws_size,
                              hipStream_t stream) {
    const float* x  = (const float*)d_in[0];
    const float* ew = (const float*)d_in[1];
    const float* W1 = (const float*)d_in[2];
    const float* b1 = (const float*)d_in[3];
    const float* W2 = (const float*)d_in[4];
    const float* b2 = (const float*)d_in[5];
    const int*   ei = (const int*)d_in[6];

    int n = in_sizes[0] / FIN;   // 100000
    int E = in_sizes[1];         // 3200000
    const int* row = ei;
    const int* col = ei + E;

    int NB   = (n + 255) >> 8;            // 391 buckets of 256 nodes
    int NN   = NB * 256;                  // padded node count
    int ABLK = (E + TILE - 1) / TILE;     // 1000 bucketize blocks
    int M1   = NB * ABLK;                 // per-(bucket,block) count matrix

    // workspace layout (4B units)
    size_t o = 0;
    int*   bcnt  = (int*)d_ws + o;  o += M1;
    int*   sbcnt = (int*)d_ws + o;  o += M1;
    int*   bsum  = (int*)d_ws + o;  o += 1024;
    int*   off   = (int*)d_ws + o;  o += (size_t)NN + 1;
    float* dinv  = (float*)((int*)d_ws + o); o += NN;
    uint*  fin   = (uint*)((int*)d_ws + o);  o += E;
    o = (o + 3) & ~(size_t)3;             // 16B align
    int2*  bpack = (int2*)((int*)d_ws + o);  // E int2 (dead after seg_build)
    // aliases into dead bpack region (8B-aligned):
    uint*  g    = (uint*)bpack;              // 8n uints (bf16x2)
    uint*  g1   = g + (size_t)8 * n;         // 8n uints

    float* outp = (float*)d_out;

    dim3 b(256);
    int G1 = (M1 + 1023) / 1024;

    // pass A: bucketize (LDS atomics only)
    bk_count_k<<<ABLK, b, 0, stream>>>(col, bcnt, E, NB, ABLK);
    scan1_k<<<G1, b, 0, stream>>>(bcnt, bsum, M1);
    scan3_k<<<G1, b, 0, stream>>>(bcnt, bsum, sbcnt, M1, G1);
    bk_scatter_k<<<ABLK, b, 0, stream>>>(row, col, ew, sbcnt, bpack, E, NB, ABLK);

    // pass B: single fused kernel (LDS edge cache + count + scan + dinv + place)
    seg_build_k<<<NB, dim3(512), 0, stream>>>(bpack, sbcnt, off, dinv, fin, E, NB, ABLK, NN);

    // dense pipeline
    gemm1_k<<<(n + 63) / 64, b, 0, stream>>>(x, W1, dinv, g, n);
    int gb4 = (n * 4 + 255) / 256;
    agg1_k<<<gb4, b, 0, stream>>>((const uint2*)g, dinv, off, fin, b1, (uint2*)g1, n);
    agg2out_k<<<gb4, b, 0, stream>>>((const uint2*)g1, dinv, off, fin, W2, b2, outp, n);
}

// Round 12
// 208.261 us; speedup vs baseline: 1.0364x; 1.0364x over previous
//
#include <hip/hip_runtime.h>
#include <hip/hip_bf16.h>

#define HID 16
#define CLS 40
#define FIN 512
#define TILE 3200     // edges per bucketize block (38KB LDS -> 4 blocks/CU)
#define NBP 512       // padded bucket count (256-node buckets; n <= 131072)
#define CAP 8704      // LDS edge cache per bucket (mean 8192, +5.7 sigma)

typedef unsigned int uint;
typedef unsigned short ushort;

__device__ __forceinline__ ushort f2bf(float f) {
    uint u = __float_as_uint(f);
    u += 0x7FFF + ((u >> 16) & 1);   // round-to-nearest-even
    return (ushort)(u >> 16);
}
__device__ __forceinline__ float bflo(uint u) { return __uint_as_float(u << 16); }
__device__ __forceinline__ float bfhi(uint u) { return __uint_as_float(u & 0xFFFF0000u); }
// decode bf15 weight packed in bits [31:17] (weights are >= 0)
__device__ __forceinline__ float wdec(uint a) {
    return __uint_as_float((a >> 17) << 16);
}

// ================= scan stage 1: per-1024-chunk sums =================
__global__ __launch_bounds__(256) void scan1_k(const int* __restrict__ cnt,
                                               int* __restrict__ bsum, int M) {
    __shared__ int ws[4];
    int b = blockIdx.x, t = threadIdx.x;
    int i0 = b * 1024 + t * 4;
    int s = 0;
#pragma unroll
    for (int q = 0; q < 4; ++q) if (i0 + q < M) s += cnt[i0 + q];
    for (int d = 32; d > 0; d >>= 1) s += __shfl_xor(s, d);
    int lane = t & 63, wid = t >> 6;
    if (lane == 0) ws[wid] = s;
    __syncthreads();
    if (t == 0) bsum[b] = ws[0] + ws[1] + ws[2] + ws[3];
}

// ============ scan stage 2 (fused): block-sum scan + element scan ===========
__global__ __launch_bounds__(256) void scan3_k(const int* __restrict__ cnt,
                                               const int* __restrict__ bsumRaw,
                                               int* __restrict__ sout, int M, int G) {
    __shared__ int sb[1024];
    __shared__ int wsumA[4], wbaseA[4];
    __shared__ int wsumB[4], wbaseB[4];
    int t = threadIdx.x;
    int lane = t & 63, wid = t >> 6;
    {   // exclusive scan of bsumRaw[0..G) into sb (every block redundantly)
        int i0 = t * 4;
        int c[4];
#pragma unroll
        for (int q = 0; q < 4; ++q) c[q] = (i0 + q < G) ? bsumRaw[i0 + q] : 0;
        int s = c[0] + c[1] + c[2] + c[3];
        int v = s;
        for (int d = 1; d < 64; d <<= 1) { int u = __shfl_up(v, d); if (lane >= d) v += u; }
        if (lane == 63) wsumA[wid] = v;
        __syncthreads();
        if (t == 0) { int r = 0; for (int q = 0; q < 4; ++q) { wbaseA[q] = r; r += wsumA[q]; } }
        __syncthreads();
        int o = v - s + wbaseA[wid];
#pragma unroll
        for (int q = 0; q < 4; ++q) { sb[i0 + q] = o; o += c[q]; }
    }
    __syncthreads();
    {   // element scan of this block's 1024 chunk
        int b = blockIdx.x;
        int i0 = b * 1024 + t * 4;
        int c[4];
#pragma unroll
        for (int q = 0; q < 4; ++q) c[q] = (i0 + q < M) ? cnt[i0 + q] : 0;
        int s = c[0] + c[1] + c[2] + c[3];
        int v = s;
        for (int d = 1; d < 64; d <<= 1) { int u = __shfl_up(v, d); if (lane >= d) v += u; }
        if (lane == 63) wsumB[wid] = v;
        __syncthreads();
        if (t == 0) { int r = 0; for (int q = 0; q < 4; ++q) { wbaseB[q] = r; r += wsumB[q]; } }
        __syncthreads();
        int o = v - s + wbaseB[wid] + sb[b];
#pragma unroll
        for (int q = 0; q < 4; ++q) {
            if (i0 + q < M) { sout[i0 + q] = o; o += c[q]; }
        }
    }
}

// ================= pass A: bucketize by col>>8 (LDS atomics only) ===========
__global__ __launch_bounds__(256) void bk_count_k(const int* __restrict__ col,
                                                  int* __restrict__ bcnt,
                                                  int E, int NB, int ABLK) {
    __shared__ int hist[NBP];
    int t = threadIdx.x, blk = blockIdx.x;
    for (int i = t; i < NBP; i += 256) hist[i] = 0;
    __syncthreads();
    int e0 = blk * TILE, e1 = min(E, e0 + TILE);
    for (int e = e0 + t; e < e1; e += 256) atomicAdd(&hist[col[e] >> 8], 1);
    __syncthreads();
    for (int b = t; b < NB; b += 256) bcnt[b * ABLK + blk] = hist[b];
}

__global__ __launch_bounds__(256) void bk_scatter_k(const int* __restrict__ row,
                                                    const int* __restrict__ col,
                                                    const float* __restrict__ w,
                                                    const int* __restrict__ sbcnt,
                                                    int2* __restrict__ bpack,
                                                    int E, int NB, int ABLK) {
    __shared__ int2 stage[TILE];
    __shared__ ushort stageB[TILE];
    __shared__ int hist[NBP], cur[NBP], gbase[NBP];
    __shared__ int wsum[4], wbase[4];
    int t = threadIdx.x, blk = blockIdx.x;
    for (int i = t; i < NBP; i += 256) hist[i] = 0;
    __syncthreads();
    int e0 = blk * TILE, e1 = min(E, e0 + TILE);
    for (int e = e0 + t; e < e1; e += 256) atomicAdd(&hist[col[e] >> 8], 1);
    __syncthreads();
    {
        int c0 = hist[2 * t], c1 = hist[2 * t + 1];
        int s = c0 + c1;
        int lane = t & 63, wid = t >> 6;
        int v = s;
        for (int d = 1; d < 64; d <<= 1) { int u = __shfl_up(v, d); if (lane >= d) v += u; }
        if (lane == 63) wsum[wid] = v;
        __syncthreads();
        if (t == 0) { int r = 0; for (int q = 0; q < 4; ++q) { wbase[q] = r; r += wsum[q]; } }
        __syncthreads();
        int excl = v - s + wbase[wid];
        int s0 = 2 * t, s1 = 2 * t + 1;
        cur[s0] = excl;
        gbase[s0] = ((s0 < NB) ? sbcnt[s0 * ABLK + blk] : 0) - excl;
        cur[s1] = excl + c0;
        gbase[s1] = ((s1 < NB) ? sbcnt[s1 * ABLK + blk] : 0) - (excl + c0);
    }
    __syncthreads();
    for (int e = e0 + t; e < e1; e += 256) {
        int c = col[e];
        int bkt = c >> 8, cl = c & 255;
        int lr = atomicAdd(&cur[bkt], 1);
        stage[lr] = make_int2(row[e] | (cl << 17), __float_as_int(w[e]));
        stageB[lr] = (ushort)bkt;
    }
    __syncthreads();
    int cntE = e1 - e0;
    for (int s = t; s < cntE; s += 256) {
        int bkt = stageB[s];
        bpack[gbase[bkt] + s] = stage[s];
    }
}

// ====== pass B (fused, 512 thr): LDS edge cache + count + scan + dinv + place
__global__ __launch_bounds__(512) void seg_build_k(const int2* __restrict__ bpack,
                                                   const int* __restrict__ sbcnt,
                                                   int* __restrict__ off,
                                                   float* __restrict__ dinv,
                                                   uint* __restrict__ fin,
                                                   int E, int NB, int ABLK, int NN) {
    __shared__ int2 ldsE[CAP];
    __shared__ int cntL[256];
    __shared__ float degL[256];
    __shared__ int curL[256];
    __shared__ int wtot[8];
    int t = threadIdx.x, b = blockIdx.x;
    if (t < 256) { cntL[t] = 0; degL[t] = 0.f; }
    __syncthreads();
    int p0 = sbcnt[b * ABLK];
    int p1 = (b + 1 < NB) ? sbcnt[(b + 1) * ABLK] : E;
    int m = p1 - p0;
    for (int j = t; j < m; j += 512) {
        int2 pk = bpack[p0 + j];
        if (j < CAP) ldsE[j] = pk;
        int cl = (pk.x >> 17) & 255;
        atomicAdd(&cntL[cl], 1);
        atomicAdd(&degL[cl], __int_as_float(pk.y));
    }
    __syncthreads();
    // exclusive scan of cntL[0..255] (threads 256..511 carry zeros)
    int c = (t < 256) ? cntL[t] : 0;
    int lane = t & 63, wid = t >> 6;
    int v = c;
    for (int d = 1; d < 64; d <<= 1) { int u = __shfl_up(v, d); if (lane >= d) v += u; }
    if (lane == 63) wtot[wid] = v;
    __syncthreads();
    if (t < 256) {
        int base = p0;
        for (int q = 0; q < wid; ++q) base += wtot[q];   // wid 0..3
        int excl = base + v - c;
        int node = b * 256 + t;
        off[node] = excl;
        curL[t] = excl;
        dinv[node] = rsqrtf(1.0f + degL[t]);   // +1 = self-loop weight
    }
    if (b == NB - 1 && t == 0) off[NN] = E;
    __syncthreads();
    for (int j = t; j < m; j += 512) {
        int2 pk = (j < CAP) ? ldsE[j] : bpack[p0 + j];   // overflow tail: re-read
        uint src = (uint)pk.x & 0x1FFFFu;
        int cl = (pk.x >> 17) & 255;
        uint u = (uint)pk.y + 0x8000u;          // raw w >= 0, bf15 round
        int pos = atomicAdd(&curL[cl], 1);
        fin[pos] = src | ((u >> 16) << 17);
    }
}

// ====== g = dinv .* (x @ W1), bf16x2-packed; 4 lanes/row, coalesced x =======
// LDS W1 layout padded: float4 index = k*4 + j + (k>>2)  (one pad f4 per 4 rows)
// -> per-instruction sub-lane stride = 17 f4 = 272 B: conflict-free (R8-verified)
__global__ __launch_bounds__(256) void gemm1_k(const float* __restrict__ x,
                                               const float* __restrict__ W1,
                                               const float* __restrict__ dinv,
                                               uint* __restrict__ g, int n) {
    __shared__ float4 w1s[FIN * HID / 4 + FIN / 4];   // 2176 f4 = 34816 B
    {
        const float4* s4 = (const float4*)W1;
        for (int i = threadIdx.x; i < FIN * HID / 4; i += 256)
            w1s[i + (i >> 4)] = s4[i];
    }
    __syncthreads();
    int r = blockIdx.x * 64 + (threadIdx.x >> 2);
    if (r >= n) return;
    int sub = threadIdx.x & 3;
    const float4* xr = (const float4*)(x + (size_t)r * FIN);
    float acc[HID];
#pragma unroll
    for (int c = 0; c < HID; ++c) acc[c] = 0.f;
    for (int q = 0; q < FIN / 16; ++q) {
        float4 xv = xr[q * 4 + sub];
        int kbase = q * 16 + sub * 4;                       // this lane's 4 rows
        const float4* w4 = &w1s[kbase * 4 + (kbase >> 2)];  // padded base
#pragma unroll
        for (int e = 0; e < 4; ++e) {
            float xe = (e == 0) ? xv.x : (e == 1) ? xv.y : (e == 2) ? xv.z : xv.w;
#pragma unroll
            for (int j = 0; j < 4; ++j) {
                float4 wv = w4[e * 4 + j];
                acc[4 * j + 0] += xe * wv.x;
                acc[4 * j + 1] += xe * wv.y;
                acc[4 * j + 2] += xe * wv.z;
                acc[4 * j + 3] += xe * wv.w;
            }
        }
    }
    // butterfly: all 4 lanes get full sums
#pragma unroll
    for (int c = 0; c < HID; ++c) {
        acc[c] += __shfl_xor(acc[c], 1, 4);
        acc[c] += __shfl_xor(acc[c], 2, 4);
    }
    // lane sub owns features 4*sub .. 4*sub+3 (constant-index selects)
    float f0, f1, f2, f3;
    {
        float t0 = (sub & 2) ? acc[8] : acc[0], t4 = (sub & 2) ? acc[12] : acc[4];
        f0 = (sub & 1) ? t4 : t0;
        float u0 = (sub & 2) ? acc[9] : acc[1], u4 = (sub & 2) ? acc[13] : acc[5];
        f1 = (sub & 1) ? u4 : u0;
        float v0 = (sub & 2) ? acc[10] : acc[2], v4 = (sub & 2) ? acc[14] : acc[6];
        f2 = (sub & 1) ? v4 : v0;
        float w0 = (sub & 2) ? acc[11] : acc[3], w4v = (sub & 2) ? acc[15] : acc[7];
        f3 = (sub & 1) ? w4v : w0;
    }
    float di = dinv[r];
    uint lo = (uint)f2bf(di * f0) | ((uint)f2bf(di * f1) << 16);
    uint hi = (uint)f2bf(di * f2) | ((uint)f2bf(di * f3) << 16);
    ((uint2*)(g + (size_t)r * 8))[sub] = make_uint2(lo, hi);
}

// ===== layer-1 gather (8 lanes/node, bf16x2/lane):
//   g1 = dinv .* relu(dinv .* (Σ w g_src + g_i) + b1)
__global__ __launch_bounds__(256) void agg1_k(const uint* __restrict__ g,
                                              const float* __restrict__ dinv,
                                              const int* __restrict__ off,
                                              const uint* __restrict__ fin,
                                              const float* __restrict__ b1,
                                              uint* __restrict__ g1, int n) {
    int tid = blockIdx.x * 256 + threadIdx.x;
    int i = tid >> 3;
    if (i >= n) return;
    int lane = tid & 7;
    uint sv = g[(size_t)i * 8 + lane];
    float lo0 = bflo(sv), hi0 = bfhi(sv);
    float lo1 = 0.f, hi1 = 0.f, lo2 = 0.f, hi2 = 0.f, lo3 = 0.f, hi3 = 0.f;
    int p = off[i], e = off[i + 1];
    for (; p + 3 < e; p += 4) {
        uint a = fin[p], b = fin[p + 1], c = fin[p + 2], d = fin[p + 3];
        uint ga = g[(size_t)(a & 0x1FFFFu) * 8 + lane];
        uint gb = g[(size_t)(b & 0x1FFFFu) * 8 + lane];
        uint gc = g[(size_t)(c & 0x1FFFFu) * 8 + lane];
        uint gd = g[(size_t)(d & 0x1FFFFu) * 8 + lane];
        float wa = wdec(a), wb = wdec(b), wc = wdec(c), wdv = wdec(d);
        lo0 += wa * bflo(ga); hi0 += wa * bfhi(ga);
        lo1 += wb * bflo(gb); hi1 += wb * bfhi(gb);
        lo2 += wc * bflo(gc); hi2 += wc * bfhi(gc);
        lo3 += wdv * bflo(gd); hi3 += wdv * bfhi(gd);
    }
    for (; p < e; ++p) {
        uint a = fin[p];
        uint ga = g[(size_t)(a & 0x1FFFFu) * 8 + lane];
        float wa = wdec(a);
        lo0 += wa * bflo(ga); hi0 += wa * bfhi(ga);
    }
    float di = dinv[i];
    float vlo = fmaxf(di * ((lo0 + lo1) + (lo2 + lo3)) + b1[2 * lane], 0.f);
    float vhi = fmaxf(di * ((hi0 + hi1) + (hi2 + hi3)) + b1[2 * lane + 1], 0.f);
    g1[(size_t)i * 8 + lane] = (uint)f2bf(di * vlo) | ((uint)f2bf(di * vhi) << 16);
}

// ===== layer-2 gather + W2 matvec + log_softmax (8 lanes/node) ==============
__global__ __launch_bounds__(256) void agg2out_k(const uint* __restrict__ g1,
                                                 const float* __restrict__ dinv,
                                                 const int* __restrict__ off,
                                                 const uint* __restrict__ fin,
                                                 const float* __restrict__ W2,
                                                 const float* __restrict__ b2,
                                                 float* __restrict__ out, int n) {
    __shared__ float w2s[HID * CLS];
    __shared__ float b2s[CLS];
    for (int q = threadIdx.x; q < HID * CLS; q += 256) w2s[q] = W2[q];
    if (threadIdx.x < CLS) b2s[threadIdx.x] = b2[threadIdx.x];
    __syncthreads();
    int tid = blockIdx.x * 256 + threadIdx.x;
    int i = tid >> 3;
    if (i >= n) return;    // 8-lane group exits together
    int lane = tid & 7;
    uint sv = g1[(size_t)i * 8 + lane];
    float lo0 = bflo(sv), hi0 = bfhi(sv);
    float lo1 = 0.f, hi1 = 0.f, lo2 = 0.f, hi2 = 0.f, lo3 = 0.f, hi3 = 0.f;
    int p = off[i], e = off[i + 1];
    for (; p + 3 < e; p += 4) {
        uint a = fin[p], b = fin[p + 1], c = fin[p + 2], d = fin[p + 3];
        uint ga = g1[(size_t)(a & 0x1FFFFu) * 8 + lane];
        uint gb = g1[(size_t)(b & 0x1FFFFu) * 8 + lane];
        uint gc = g1[(size_t)(c & 0x1FFFFu) * 8 + lane];
        uint gd = g1[(size_t)(d & 0x1FFFFu) * 8 + lane];
        float wa = wdec(a), wb = wdec(b), wc = wdec(c), wdv = wdec(d);
        lo0 += wa * bflo(ga); hi0 += wa * bfhi(ga);
        lo1 += wb * bflo(gb); hi1 += wb * bfhi(gb);
        lo2 += wc * bflo(gc); hi2 += wc * bfhi(gc);
        lo3 += wdv * bflo(gd); hi3 += wdv * bfhi(gd);
    }
    for (; p < e; ++p) {
        uint a = fin[p];
        uint ga = g1[(size_t)(a & 0x1FFFFu) * 8 + lane];
        float wa = wdec(a);
        lo0 += wa * bflo(ga); hi0 += wa * bfhi(ga);
    }
    float di = dinv[i];
    float vlo = di * ((lo0 + lo1) + (lo2 + lo3));   // agg2[i][2*lane]
    float vhi = di * ((hi0 + hi1) + (hi2 + hi3));   // agg2[i][2*lane+1]
    // transpose within 8-lane group: a[k] = agg2[i][k]
    float a[HID];
#pragma unroll
    for (int k = 0; k < 8; ++k) {
        a[2 * k]     = __shfl(vlo, k, 8);
        a[2 * k + 1] = __shfl(vhi, k, 8);
    }
    // each lane computes classes lane + 8*j, j = 0..4
    float z[5];
#pragma unroll
    for (int j = 0; j < 5; ++j) z[j] = b2s[lane + 8 * j];
#pragma unroll
    for (int k = 0; k < HID; ++k) {
        float ak = a[k];
#pragma unroll
        for (int j = 0; j < 5; ++j) z[j] += ak * w2s[k * CLS + lane + 8 * j];
    }
    float m = z[0];
#pragma unroll
    for (int j = 1; j < 5; ++j) m = fmaxf(m, z[j]);
#pragma unroll
    for (int d = 1; d < 8; d <<= 1) m = fmaxf(m, __shfl_xor(m, d, 8));
    float s = 0.f;
#pragma unroll
    for (int j = 0; j < 5; ++j) s += __expf(z[j] - m);
#pragma unroll
    for (int d = 1; d < 8; d <<= 1) s += __shfl_xor(s, d, 8);
    float l = __logf(s) + m;
    float* o = out + (size_t)i * CLS;
#pragma unroll
    for (int j = 0; j < 5; ++j) o[lane + 8 * j] = z[j] - l;
}

extern "C" void kernel_launch(void* const* d_in, const int* in_sizes, int n_in,
                              void* d_out, int out_size, void* d_ws, size_t ws_size,
                              hipStream_t stream) {
    const float* x  = (const float*)d_in[0];
    const float* ew = (const float*)d_in[1];
    const float* W1 = (const float*)d_in[2];
    const float* b1 = (const float*)d_in[3];
    const float* W2 = (const float*)d_in[4];
    const float* b2 = (const float*)d_in[5];
    const int*   ei = (const int*)d_in[6];

    int n = in_sizes[0] / FIN;   // 100000
    int E = in_sizes[1];         // 3200000
    const int* row = ei;
    const int* col = ei + E;

    int NB   = (n + 255) >> 8;            // 391 buckets of 256 nodes
    int NN   = NB * 256;                  // padded node count
    int ABLK = (E + TILE - 1) / TILE;     // 1000 bucketize blocks
    int M1   = NB * ABLK;                 // per-(bucket,block) count matrix

    // workspace layout (4B units)
    size_t o = 0;
    int*   bcnt  = (int*)d_ws + o;  o += M1;
    int*   sbcnt = (int*)d_ws + o;  o += M1;
    int*   bsum  = (int*)d_ws + o;  o += 1024;
    int*   off   = (int*)d_ws + o;  o += (size_t)NN + 1;
    float* dinv  = (float*)((int*)d_ws + o); o += NN;
    uint*  fin   = (uint*)((int*)d_ws + o);  o += E;
    o = (o + 3) & ~(size_t)3;             // 16B align
    int2*  bpack = (int2*)((int*)d_ws + o);  // E int2 (dead after seg_build)
    // aliases into dead bpack region:
    uint*  g    = (uint*)bpack;              // 8n uints (bf16x2)
    uint*  g1   = g + (size_t)8 * n;         // 8n uints

    float* outp = (float*)d_out;

    dim3 b(256);
    int G1 = (M1 + 1023) / 1024;

    // pass A: bucketize (LDS atomics only)
    bk_count_k<<<ABLK, b, 0, stream>>>(col, bcnt, E, NB, ABLK);
    scan1_k<<<G1, b, 0, stream>>>(bcnt, bsum, M1);
    scan3_k<<<G1, b, 0, stream>>>(bcnt, bsum, sbcnt, M1, G1);
    bk_scatter_k<<<ABLK, b, 0, stream>>>(row, col, ew, sbcnt, bpack, E, NB, ABLK);

    // pass B: single fused kernel (LDS edge cache + count + scan + dinv + place)
    seg_build_k<<<NB, dim3(512), 0, stream>>>(bpack, sbcnt, off, dinv, fin, E, NB, ABLK, NN);

    // dense pipeline
    gemm1_k<<<(n + 63) / 64, b, 0, stream>>>(x, W1, dinv, g, n);
    int gb8 = (n * 8 + 255) / 256;
    agg1_k<<<gb8, b, 0, stream>>>(g, dinv, off, fin, b1, g1, n);
    agg2out_k<<<gb8, b, 0, stream>>>(g1, dinv, off, fin, W2, b2, outp, n);
}